// Round 9
// baseline (366.752 us; speedup 1.0000x reference)
//
#include <hip/hip_runtime.h>
#include <hip/hip_bf16.h>
#include <cstdint>
#include <cstddef>

// Problem dims (fixed)
#define BB 16
#define LL 2048
#define MM (BB * LL)   // 32768 rows
#define KK 1024        // inner dim
#define HH 1024        // hidden per gate

typedef __attribute__((ext_vector_type(8))) short bf16x8;
typedef __attribute__((ext_vector_type(4))) float f32x4;

// ---------- fp32 -> bf16 (RNE) ----------
__device__ __forceinline__ unsigned short f2bf(float f) {
    unsigned u = __builtin_bit_cast(unsigned, f);
    u += 0x7fffu + ((u >> 16) & 1u);
    return (unsigned short)(u >> 16);
}

__global__ void cvt_f32_to_bf16(const float* __restrict__ in,
                                unsigned short* __restrict__ out, int n8) {
    int i = blockIdx.x * blockDim.x + threadIdx.x;
    if (i >= n8) return;
    const float4* p = reinterpret_cast<const float4*>(in) + (size_t)i * 2;
    float4 v0 = p[0];
    float4 v1 = p[1];
    union { unsigned short us[8]; uint4 v; } o;
    o.us[0] = f2bf(v0.x); o.us[1] = f2bf(v0.y);
    o.us[2] = f2bf(v0.z); o.us[3] = f2bf(v0.w);
    o.us[4] = f2bf(v1.x); o.us[5] = f2bf(v1.y);
    o.us[6] = f2bf(v1.z); o.us[7] = f2bf(v1.w);
    reinterpret_cast<uint4*>(out)[i] = o.v;
}

// ---------- mask scan ----------
__global__ __launch_bounds__(1024) void scan_mask(const int* __restrict__ mask,
                                                  int* __restrict__ rows,
                                                  int* __restrict__ Na) {
    __shared__ int psum[1024];
    const int t = threadIdx.x;
    const int base = t * 32;
    int m[32];
    int cnt = 0;
#pragma unroll
    for (int i = 0; i < 32; ++i) { m[i] = mask[base + i]; cnt += (m[i] != 0); }
    psum[t] = cnt;
    __syncthreads();
    for (int off = 1; off < 1024; off <<= 1) {
        int v = (t >= off) ? psum[t - off] : 0;
        __syncthreads();
        psum[t] += v;
        __syncthreads();
    }
    int offset = psum[t] - cnt;
#pragma unroll
    for (int i = 0; i < 32; ++i) {
        if (m[i]) rows[offset++] = base + i;
    }
    if (t == 1023) *Na = psum[1023];
}

// ---------- gather active rows of x, f32 -> bf16 ----------
__global__ __launch_bounds__(256) void gather_cvt(const float* __restrict__ x,
                                                  const int* __restrict__ rows,
                                                  const int* __restrict__ Na,
                                                  unsigned short* __restrict__ xbf) {
    const int j = blockIdx.x;
    if (j >= *Na) return;
    const int r = rows[j];
    const float4 v = reinterpret_cast<const float4*>(x + (size_t)r * KK)[threadIdx.x];
    ushort4 o;
    o.x = f2bf(v.x); o.y = f2bf(v.y); o.z = f2bf(v.z); o.w = f2bf(v.w);
    reinterpret_cast<ushort4*>(xbf + (size_t)j * KK)[threadIdx.x] = o;
}

// ---------- exact zeros for masked-out output rows ----------
__global__ __launch_bounds__(256) void zero_masked(const int* __restrict__ mask,
                                                   float* __restrict__ out) {
    const int m = blockIdx.x;
    if (mask[m] != 0) return;
    const int bb = m >> 11;
    const int ll = m & 2047;
    float4 z = {0.f, 0.f, 0.f, 0.f};
    reinterpret_cast<float4*>(out + ((size_t)ll * BB + bb) * HH)[threadIdx.x] = z;
}

// ---------- async global->LDS, 16B per lane ----------
__device__ __forceinline__ void gload16(const unsigned short* g, unsigned short* l) {
    __builtin_amdgcn_global_load_lds(
        (const __attribute__((address_space(1))) unsigned int*)g,
        (__attribute__((address_space(3))) unsigned int*)l,
        16, 0, 0);
}

#define WAITVM0  asm volatile("s_waitcnt vmcnt(0)" ::: "memory")
#define SB       __builtin_amdgcn_sched_barrier(0)
#define BAR      __builtin_amdgcn_s_barrier()

// ---------- fused GEMM + GRU gating: R6 skeleton, BK=64 ----------
// BM=128, BN=64 x 3 gates, BK=64, 256 threads (4 waves, 2M x 2N).
// 2 buffers x 20480 shorts (40KB) = 80KB LDS -> exactly 2 blocks/CU.
// Buffer units (4096 shorts each): A0(rows 0-63) A1(64-127) B0 B1 B2.
// Row = 128B = 8 slots of 16B. Swizzle: chunk c of row r stored at slot
// c ^ (r&7)  -> each bank serves exactly 8B per quarter-wave b128 read
// (balanced, conflict-free). Inverse-swizzle applied to global source
// (rule #21): staging thread t covers row t>>3 (per 32-row call), slot t&7,
// so it must fetch global k-chunk (t&7)^((t>>3)&7).
// Per tile: 10 gloads (5 units x 2 calls), 20 ds_read_b128, 48 MFMA.
// COMPUTE issues all 20 reads before the MFMAs: compiler's fine-grained
// lgkm waits let ksub-1 reads flow underneath ksub-0 MFMAs (intra-wave ILP;
// with acc=96 fixed, 2 waves/SIMD is a hard cap, so ILP must come from here).
// 16 tiles -> half the barriers/drains of BK=32; ~1900-cyc compute window
// fully covers the 10-load HBM latency before the per-tile vmcnt(0).
template <int MODE>
__global__ __launch_bounds__(256, 2) void gru_layer(
    const unsigned short* __restrict__ A,
    const unsigned short* __restrict__ W,
    const float* __restrict__ b_ih,
    const float* __restrict__ b_hh,
    const int* __restrict__ rows,
    const int* __restrict__ Na_p,
    unsigned short* __restrict__ out_bf,
    float* __restrict__ out_f) {
    __shared__ unsigned short lds[2][20480];  // 81920 B

    const int Na = *Na_p;
    const int m0 = blockIdx.x * 128;
    if (m0 >= Na) return;
    const int n0 = blockIdx.y * 64;

    const int tid  = threadIdx.x;
    const int lane = tid & 63;
    const int wid  = tid >> 6;
    const int wr   = wid >> 1;  // 0..1
    const int wc   = wid & 1;   // 0..1

    // --- staging sources: call k (k=0,1) covers rows k*32 + (tid>>3), slot tid&7 ---
    const int trow = tid >> 3;                               // 0..31 within call
    const int tcol = ((tid & 7) ^ (trow & 7)) * 8;           // inverse-swizzled chunk
    // A pointers per (unit u, call c): row = m0 + u*64 + c*32 + trow, clamped
    const unsigned short* ap[2][2];
#pragma unroll
    for (int u = 0; u < 2; ++u)
#pragma unroll
        for (int c = 0; c < 2; ++c) {
            int r = m0 + u * 64 + c * 32 + trow;
            if (r >= Na) r = Na - 1;
            ap[u][c] = A + (size_t)r * KK + tcol;
        }
    // B pointers per gate (call handled by static +32*KK): row = g*HH + n0 + trow
    const unsigned short* bp[3];
#pragma unroll
    for (int g = 0; g < 3; ++g)
        bp[g] = W + (size_t)(g * HH + n0 + trow) * KK + tcol;

    // dst (shorts): unit*4096 + call*2048 + wid*512 (lane*16B appended by HW)
#define STAGE(kt, buf) do {                                                   \
        const int _o = (kt) * 64;                                             \
        unsigned short* D = &lds[(buf)][wid * 512];                           \
        gload16(ap[0][0] + _o, D + 0 * 4096 + 0 * 2048);                      \
        gload16(ap[0][1] + _o, D + 0 * 4096 + 1 * 2048);                      \
        gload16(ap[1][0] + _o, D + 1 * 4096 + 0 * 2048);                      \
        gload16(ap[1][1] + _o, D + 1 * 4096 + 1 * 2048);                      \
        gload16(bp[0] + _o, D + 2 * 4096 + 0 * 2048);                         \
        gload16(bp[0] + 32 * KK + _o, D + 2 * 4096 + 1 * 2048);               \
        gload16(bp[1] + _o, D + 3 * 4096 + 0 * 2048);                         \
        gload16(bp[1] + 32 * KK + _o, D + 3 * 4096 + 1 * 2048);               \
        gload16(bp[2] + _o, D + 4 * 4096 + 0 * 2048);                         \
        gload16(bp[2] + 32 * KK + _o, D + 4 * 4096 + 1 * 2048);               \
    } while (0)

    // --- read offsets (shorts): row r at r*64; chunk c at slot c^(r&7) ---
    // lane l: row = base + (l&15), chunk = ksub*4 + (l>>4); (r&7) == (l&7)&7? no:
    // r&7 = (base&7 + l15)&7 with base multiple of 16 -> r&7 = l15&7.
    const int l15 = lane & 15;
    const int r7  = l15 & 7;
    const int akp0 = (((0 * 4 + (lane >> 4)) ^ r7) << 3);   // ksub 0 slot*8
    const int akp1 = (((1 * 4 + (lane >> 4)) ^ r7) << 3);   // ksub 1 slot*8
    int aoff[4], boff[3];
#pragma unroll
    for (int mf = 0; mf < 4; ++mf)
        aoff[mf] = wr * 4096 + (mf * 16 + l15) * 64;        // unit A{wr}
#pragma unroll
    for (int g = 0; g < 3; ++g)
        boff[g] = (2 + g) * 4096 + (wc * 32 + l15) * 64;    // nf adds 16*64

    f32x4 accr[4][2] = {};
    f32x4 accz[4][2] = {};
    f32x4 accn[4][2] = {};

    // COMPUTE: all 20 ds_reads first (both ksubs), then 48 MFMAs.
#define COMPUTE(Lp) do {                                                           \
        bf16x8 af0[4], af1[4], bfr0[2][3], bfr1[2][3];                             \
        _Pragma("unroll") for (int mf = 0; mf < 4; ++mf) {                         \
            af0[mf] = *reinterpret_cast<const bf16x8*>(&(Lp)[aoff[mf] + akp0]);    \
            af1[mf] = *reinterpret_cast<const bf16x8*>(&(Lp)[aoff[mf] + akp1]);    \
        }                                                                          \
        _Pragma("unroll") for (int nf = 0; nf < 2; ++nf)                           \
            _Pragma("unroll") for (int g = 0; g < 3; ++g) {                        \
                bfr0[nf][g] = *reinterpret_cast<const bf16x8*>(                    \
                    &(Lp)[boff[g] + nf * 1024 + akp0]);                            \
                bfr1[nf][g] = *reinterpret_cast<const bf16x8*>(                    \
                    &(Lp)[boff[g] + nf * 1024 + akp1]);                            \
            }                                                                      \
        __builtin_amdgcn_s_setprio(1);                                             \
        _Pragma("unroll") for (int nf = 0; nf < 2; ++nf)                           \
            _Pragma("unroll") for (int mf = 0; mf < 4; ++mf) {                     \
                accr[mf][nf] = __builtin_amdgcn_mfma_f32_16x16x32_bf16(            \
                    af0[mf], bfr0[nf][0], accr[mf][nf], 0, 0, 0);                  \
                accz[mf][nf] = __builtin_amdgcn_mfma_f32_16x16x32_bf16(            \
                    af0[mf], bfr0[nf][1], accz[mf][nf], 0, 0, 0);                  \
                accn[mf][nf] = __builtin_amdgcn_mfma_f32_16x16x32_bf16(            \
                    af0[mf], bfr0[nf][2], accn[mf][nf], 0, 0, 0);                  \
            }                                                                      \
        _Pragma("unroll") for (int nf = 0; nf < 2; ++nf)                           \
            _Pragma("unroll") for (int mf = 0; mf < 4; ++mf) {                     \
                accr[mf][nf] = __builtin_amdgcn_mfma_f32_16x16x32_bf16(            \
                    af1[mf], bfr1[nf][0], accr[mf][nf], 0, 0, 0);                  \
                accz[mf][nf] = __builtin_amdgcn_mfma_f32_16x16x32_bf16(            \
                    af1[mf], bfr1[nf][1], accz[mf][nf], 0, 0, 0);                  \
                accn[mf][nf] = __builtin_amdgcn_mfma_f32_16x16x32_bf16(            \
                    af1[mf], bfr1[nf][2], accn[mf][nf], 0, 0, 0);                  \
            }                                                                      \
        __builtin_amdgcn_s_setprio(0);                                             \
    } while (0)

    // prologue: stage tile 0, drain, barrier
    STAGE(0, 0);
    WAITVM0; BAR; SB;

    int cur = 0;
#pragma unroll 1
    for (int kt = 0; kt < 15; ++kt) {
        STAGE(kt + 1, cur ^ 1);          // issue next-tile loads FIRST
        const unsigned short* L = &lds[cur][0];
        COMPUTE(L);                       // 20 reads + 48 MFMA hide the latency
        WAITVM0; BAR; SB;                 // drain after compute, once per tile
        cur ^= 1;
    }
    {   // peeled last tile: no staging
        const unsigned short* L = &lds[cur][0];
        COMPUTE(L);
    }

    // --- epilogue: gating; C/D layout col = lane&15, row = (lane>>4)*4 + j ---
#pragma unroll
    for (int nf = 0; nf < 2; ++nf) {
        const int col = n0 + wc * 32 + nf * 16 + l15;
        const float br_b = b_ih[col] + b_hh[col];
        const float bz_b = b_ih[HH + col] + b_hh[HH + col];
        const float bn_i = b_ih[2 * HH + col];
        const float bn_h = b_hh[2 * HH + col];
#pragma unroll
        for (int mf = 0; mf < 4; ++mf) {
#pragma unroll
            for (int j = 0; j < 4; ++j) {
                const int row = m0 + wr * 64 + mf * 16 + (lane >> 4) * 4 + j;
                if (row >= Na) continue;
                const float r = 1.f / (1.f + __expf(-(accr[mf][nf][j] + br_b)));
                const float z = 1.f / (1.f + __expf(-(accz[mf][nf][j] + bz_b)));
                const float n = tanhf(accn[mf][nf][j] + bn_i + r * bn_h);
                const float h = (1.f - z) * n;
                if (MODE == 0) {
                    out_bf[(size_t)row * HH + col] = f2bf(h);
                } else {
                    const int orig = rows[row];
                    const int bb = orig >> 11;
                    const int ll = orig & 2047;
                    out_f[((size_t)ll * BB + bb) * HH + col] = h;
                }
            }
        }
    }
#undef STAGE
#undef COMPUTE
}

extern "C" void kernel_launch(void* const* d_in, const int* in_sizes, int n_in,
                              void* d_out, int out_size, void* d_ws, size_t ws_size,
                              hipStream_t stream) {
    const float* x   = (const float*)d_in[0];
    const int*   msk = (const int*)d_in[1];
    const float* W0  = (const float*)d_in[2];
    const float* bi0 = (const float*)d_in[4];
    const float* bh0 = (const float*)d_in[5];
    const float* W1  = (const float*)d_in[6];
    const float* bi1 = (const float*)d_in[8];
    const float* bh1 = (const float*)d_in[9];
    float* out = (float*)d_out;

    char* ws = (char*)d_ws;
    unsigned short* xbf  = (unsigned short*)ws;                  // 67,108,864 B (worst case)
    unsigned short* h1bf = (unsigned short*)(ws + 67108864);     // 67,108,864 B (worst case)
    unsigned short* w0bf = (unsigned short*)(ws + 134217728);    //  6,291,456 B
    unsigned short* w1bf = (unsigned short*)(ws + 140509184);    //  6,291,456 B
    int* rows = (int*)(ws + 146800640);                          //    131,072 B
    int* Na   = (int*)(ws + 146931712);                          //          4 B

    scan_mask<<<1, 1024, 0, stream>>>(msk, rows, Na);

    cvt_f32_to_bf16<<<1536, 256, 0, stream>>>(W0, w0bf, 3 * HH * KK / 8);
    cvt_f32_to_bf16<<<1536, 256, 0, stream>>>(W1, w1bf, 3 * HH * KK / 8);

    zero_masked<<<MM, 256, 0, stream>>>(msk, out);
    gather_cvt<<<MM, 256, 0, stream>>>(x, rows, Na, xbf);

    dim3 grid(MM / 128, HH / 64);  // (256, 16) worst case; blocks past Na exit
    gru_layer<0><<<grid, 256, 0, stream>>>(xbf, w0bf, bi0, bh0, rows, Na, h1bf, nullptr);
    gru_layer<1><<<grid, 256, 0, stream>>>(h1bf, w1bf, bi1, bh1, rows, Na, nullptr, out);
}